// Round 2
// baseline (803.045 us; speedup 1.0000x reference)
//
#include <hip/hip_runtime.h>

// Segmented mean: x[N][64] fp32, seg[N] int32 (sorted, contiguous), len[B] int32.
// out[B][64] = segment_sum(x) / len.
//
// Memory-bound: 256 MB read -> ~41 us floor at 6.3 TB/s (x is exactly 256 MiB,
// so a large fraction is L3-resident across bench iterations -- use CACHED
// loads; nontemporal loads regressed 150->303 us by forcing the HBM miss path).
// Structure exploited: min segment length ~8100 rows >> ROWS_PER_BLOCK, so a
// 512-row block spans <=2 segments; ~63/2048 blocks contain a boundary.
// Fast path (full uniform block): fully-unrolled 32x float4 loads with 4
// independent accumulators -> deep MLP, no per-row seg loads, no branches.
// No d_ws usage; last block divides in place (fused; self-cleaning counter).

#define D 64
#define ROWS_PER_BLOCK 512
#define NTHREADS 256

typedef float f32x4 __attribute__((ext_vector_type(4)));

// Zero-initialized at module load; last block resets it for the next replay.
__device__ int g_done_counter = 0;

__global__ __launch_bounds__(NTHREADS) void seg_mean_kernel(
    const float* __restrict__ x,
    const int*   __restrict__ seg,
    const int*   __restrict__ len,
    float*       __restrict__ out,    // [B][D], pre-zeroed; accumulator + output
    int n_rows, int total)
{
    __shared__ float lacc[2][D];
    __shared__ int sBoundary, sNb, sIsLast;

    const int tid = threadIdx.x;
    const int r0  = blockIdx.x * ROWS_PER_BLOCK;
    int r1 = r0 + ROWS_PER_BLOCK;
    if (r1 > n_rows) r1 = n_rows;

    // thread layout: 16 col-groups (float4) x 16 row-lanes
    // -> one wave loads 4 consecutive rows x 64 cols = 1 KB contiguous
    const int col     = (tid & 15) * 4;
    const int rowlane = tid >> 4;

    if (r0 < n_rows) {   // block-uniform
        const int s0 = seg[r0];
        const int sN = seg[r1 - 1];

        for (int i = tid; i < 2 * D; i += NTHREADS) ((float*)lacc)[i] = 0.0f;
        if (tid == 0) { sBoundary = r1; sNb = 0; }
        __syncthreads();

        int boundary = r1, nb = 0;
        if (s0 != sN) {  // only ~63/2048 blocks scan for the boundary
            for (int i = r0 + 1 + tid; i < r1; i += NTHREADS) {
                if (seg[i] != seg[i - 1]) { atomicAdd(&sNb, 1); atomicMin(&sBoundary, i); }
            }
            __syncthreads();
            boundary = sBoundary;
            nb       = sNb;
        }

        if (nb <= 1) {
            f32x4 a0 = {0.f, 0.f, 0.f, 0.f};
            f32x4 a1 = {0.f, 0.f, 0.f, 0.f};

            if (boundary >= r1 && (r1 - r0) == ROWS_PER_BLOCK) {
                // ---- fast path: full uniform block, exactly 32 loads/thread,
                //      4 independent accumulators to break the dep chain ----
                const float* p = x + (size_t)(r0 + rowlane) * D + col;
                f32x4 t0 = {0.f,0.f,0.f,0.f}, t1 = {0.f,0.f,0.f,0.f};
                f32x4 t2 = {0.f,0.f,0.f,0.f}, t3 = {0.f,0.f,0.f,0.f};
                #pragma unroll
                for (int it = 0; it < 8; ++it) {
                    const int base = it * 64;   // rows; 4 slots at stride 16
                    t0 += *reinterpret_cast<const f32x4*>(p + (base +  0) * D);
                    t1 += *reinterpret_cast<const f32x4*>(p + (base + 16) * D);
                    t2 += *reinterpret_cast<const f32x4*>(p + (base + 32) * D);
                    t3 += *reinterpret_cast<const f32x4*>(p + (base + 48) * D);
                }
                a0 = (t0 + t1) + (t2 + t3);
            } else {
                // boundary (or tail) block: predicated two-accumulator loop
                for (int r = r0 + rowlane; r < r1; r += 16) {
                    const f32x4 v = *reinterpret_cast<const f32x4*>(
                        x + (size_t)r * D + col);
                    if (r < boundary) { a0 += v; } else { a1 += v; }
                }
            }

            atomicAdd(&lacc[0][col + 0], a0.x);
            atomicAdd(&lacc[0][col + 1], a0.y);
            atomicAdd(&lacc[0][col + 2], a0.z);
            atomicAdd(&lacc[0][col + 3], a0.w);
            if (boundary < r1) {
                atomicAdd(&lacc[1][col + 0], a1.x);
                atomicAdd(&lacc[1][col + 1], a1.y);
                atomicAdd(&lacc[1][col + 2], a1.z);
                atomicAdd(&lacc[1][col + 3], a1.w);
            }
            __syncthreads();
            if (tid < D) {
                atomicAdd(&out[(size_t)s0 * D + tid], lacc[0][tid]);
                if (boundary < r1)
                    atomicAdd(&out[(size_t)sN * D + tid], lacc[1][tid]);
            }
        } else {
            // ---- general fallback (not expected on this data) ----
            f32x4 a = {0.f, 0.f, 0.f, 0.f};
            int cur = -1;
            for (int r = r0 + rowlane; r < r1; r += 16) {
                const int s = seg[r];
                const f32x4 v = *reinterpret_cast<const f32x4*>(x + (size_t)r * D + col);
                if (s != cur) {
                    if (cur >= 0) {
                        atomicAdd(&out[(size_t)cur * D + col + 0], a.x);
                        atomicAdd(&out[(size_t)cur * D + col + 1], a.y);
                        atomicAdd(&out[(size_t)cur * D + col + 2], a.z);
                        atomicAdd(&out[(size_t)cur * D + col + 3], a.w);
                    }
                    a = {0.f, 0.f, 0.f, 0.f};
                    cur = s;
                }
                a += v;
            }
            if (cur >= 0) {
                atomicAdd(&out[(size_t)cur * D + col + 0], a.x);
                atomicAdd(&out[(size_t)cur * D + col + 1], a.y);
                atomicAdd(&out[(size_t)cur * D + col + 2], a.z);
                atomicAdd(&out[(size_t)cur * D + col + 3], a.w);
            }
        }
    }

    // ---- completion detection + fused divide (last block) ----
    __threadfence();       // release: make this block's global atomics visible
    __syncthreads();
    if (tid == 0) {
        const int prev = __hip_atomic_fetch_add(&g_done_counter, 1,
                             __ATOMIC_ACQ_REL, __HIP_MEMORY_SCOPE_AGENT);
        sIsLast = (prev == (int)gridDim.x - 1);
    }
    __syncthreads();
    if (sIsLast) {         // block-uniform
        if (tid == 0)      // self-clean for the next graph replay
            __hip_atomic_store(&g_done_counter, 0,
                               __ATOMIC_RELAXED, __HIP_MEMORY_SCOPE_AGENT);
        for (int i = tid; i < total; i += NTHREADS) {
            // agent-scope atomic load: read the coherence point, not a
            // possibly-stale per-XCD L2 line (G16)
            const float v = __hip_atomic_load(&out[i],
                                __ATOMIC_RELAXED, __HIP_MEMORY_SCOPE_AGENT);
            out[i] = v / (float)len[i >> 6];   // i>>6 == segment (D=64)
        }
    }
}

extern "C" void kernel_launch(void* const* d_in, const int* in_sizes, int n_in,
                              void* d_out, int out_size, void* d_ws, size_t ws_size,
                              hipStream_t stream) {
    const float* x   = (const float*)d_in[0];
    const int*   seg = (const int*)d_in[1];
    const int*   len = (const int*)d_in[2];
    float*       out = (float*)d_out;

    const int n_rows = in_sizes[1];       // N = 1048576
    const int B      = in_sizes[2];       // 64
    const int total  = B * D;             // 4096 == out_size

    // out doubles as the accumulator: zero it (out is poisoned before each call)
    hipMemsetAsync(out, 0, (size_t)total * sizeof(float), stream);

    const int grid = (n_rows + ROWS_PER_BLOCK - 1) / ROWS_PER_BLOCK;  // 2048
    seg_mean_kernel<<<grid, NTHREADS, 0, stream>>>(x, seg, len, out, n_rows, total);
}

// Round 3
// 374.448 us; speedup vs baseline: 2.1446x; 2.1446x over previous
//
#include <hip/hip_runtime.h>

// Segmented mean: x[N][64] fp32, seg[N] int32 (sorted, contiguous), len[B] int32.
// out[B][64] = segment_sum(x) / len.
//
// Memory-bound: 256 MB read -> ~41 us floor at 6.3 TB/s.
// Structure exploited: min segment length ~8100 rows >> ROWS_PER_BLOCK, so a
// 512-row block spans <=2 segments; ~63/2048 blocks contain a boundary.
//
// Lessons encoded here (rounds 1-2 post-mortems):
//  * NO d_ws usage: the harness's 1 GiB ws poison fill (160 us dispatches)
//    only happens when ws is used. Accumulate directly into out (16 KB).
//  * NO in-kernel device fences / done-counter fused divide: 2048 per-block
//    __threadfence (L2 writeback) + acquire RMW (L2 invalidate) poisoned the
//    memory system -> 550 us at 0.4% VALUBusy even when data was L3-resident.
//    The kernel boundary is the sync: two kernels, zero fences.
//  * CACHED loads (x is 256 MiB, substantially L3-resident across replays);
//    nontemporal loads force the HBM-miss path (round-1 regression).
//  * Fast path for uniform blocks: fully-unrolled 32x float4 loads, 4
//    independent accumulators, no per-row seg loads, no per-row branches.

#define D 64
#define ROWS_PER_BLOCK 512
#define NTHREADS 256

typedef float f32x4 __attribute__((ext_vector_type(4)));

__global__ __launch_bounds__(NTHREADS) void seg_sum_kernel(
    const float* __restrict__ x,
    const int*   __restrict__ seg,
    float*       __restrict__ out,    // [B][D] fp32, pre-zeroed accumulator
    int n_rows)
{
    __shared__ float lacc[2][D];
    __shared__ int sBoundary, sNb;

    const int tid = threadIdx.x;
    const int r0  = blockIdx.x * ROWS_PER_BLOCK;
    if (r0 >= n_rows) return;   // uniform across block
    int r1 = r0 + ROWS_PER_BLOCK;
    if (r1 > n_rows) r1 = n_rows;

    // thread layout: 16 col-groups (float4) x 16 row-lanes
    // -> one wave covers 4 consecutive rows x 64 cols = 1 KB contiguous
    const int col     = (tid & 15) * 4;
    const int rowlane = tid >> 4;

    const int s0 = seg[r0];
    const int sN = seg[r1 - 1];

    for (int i = tid; i < 2 * D; i += NTHREADS) ((float*)lacc)[i] = 0.0f;
    if (tid == 0) { sBoundary = r1; sNb = 0; }
    __syncthreads();

    int boundary = r1, nb = 0;
    if (s0 != sN) {  // only ~63/2048 blocks scan for the boundary
        for (int i = r0 + 1 + tid; i < r1; i += NTHREADS) {
            if (seg[i] != seg[i - 1]) { atomicAdd(&sNb, 1); atomicMin(&sBoundary, i); }
        }
        __syncthreads();
        boundary = sBoundary;
        nb       = sNb;
    }

    if (nb <= 1) {
        f32x4 a0 = {0.f, 0.f, 0.f, 0.f};
        f32x4 a1 = {0.f, 0.f, 0.f, 0.f};

        if (boundary >= r1 && (r1 - r0) == ROWS_PER_BLOCK) {
            // ---- fast path: full uniform block, exactly 32 loads/thread,
            //      4 independent accumulators to break the dep chain ----
            const float* p = x + (size_t)(r0 + rowlane) * D + col;
            f32x4 t0 = {0.f,0.f,0.f,0.f}, t1 = {0.f,0.f,0.f,0.f};
            f32x4 t2 = {0.f,0.f,0.f,0.f}, t3 = {0.f,0.f,0.f,0.f};
            #pragma unroll
            for (int it = 0; it < 8; ++it) {
                const int base = it * 64;   // rows; 4 slots at stride 16
                t0 += *reinterpret_cast<const f32x4*>(p + (base +  0) * D);
                t1 += *reinterpret_cast<const f32x4*>(p + (base + 16) * D);
                t2 += *reinterpret_cast<const f32x4*>(p + (base + 32) * D);
                t3 += *reinterpret_cast<const f32x4*>(p + (base + 48) * D);
            }
            a0 = (t0 + t1) + (t2 + t3);
        } else {
            // boundary (or tail) block: predicated two-accumulator loop
            for (int r = r0 + rowlane; r < r1; r += 16) {
                const f32x4 v = *reinterpret_cast<const f32x4*>(
                    x + (size_t)r * D + col);
                if (r < boundary) { a0 += v; } else { a1 += v; }
            }
        }

        atomicAdd(&lacc[0][col + 0], a0.x);
        atomicAdd(&lacc[0][col + 1], a0.y);
        atomicAdd(&lacc[0][col + 2], a0.z);
        atomicAdd(&lacc[0][col + 3], a0.w);
        if (boundary < r1) {
            atomicAdd(&lacc[1][col + 0], a1.x);
            atomicAdd(&lacc[1][col + 1], a1.y);
            atomicAdd(&lacc[1][col + 2], a1.z);
            atomicAdd(&lacc[1][col + 3], a1.w);
        }
        __syncthreads();
        if (tid < D) {
            atomicAdd(&out[(size_t)s0 * D + tid], lacc[0][tid]);
            if (boundary < r1)
                atomicAdd(&out[(size_t)sN * D + tid], lacc[1][tid]);
        }
    } else {
        // ---- general fallback (not expected on this data) ----
        f32x4 a = {0.f, 0.f, 0.f, 0.f};
        int cur = -1;
        for (int r = r0 + rowlane; r < r1; r += 16) {
            const int s = seg[r];
            const f32x4 v = *reinterpret_cast<const f32x4*>(x + (size_t)r * D + col);
            if (s != cur) {
                if (cur >= 0) {
                    atomicAdd(&out[(size_t)cur * D + col + 0], a.x);
                    atomicAdd(&out[(size_t)cur * D + col + 1], a.y);
                    atomicAdd(&out[(size_t)cur * D + col + 2], a.z);
                    atomicAdd(&out[(size_t)cur * D + col + 3], a.w);
                }
                a = {0.f, 0.f, 0.f, 0.f};
                cur = s;
            }
            a += v;
        }
        if (cur >= 0) {
            atomicAdd(&out[(size_t)cur * D + col + 0], a.x);
            atomicAdd(&out[(size_t)cur * D + col + 1], a.y);
            atomicAdd(&out[(size_t)cur * D + col + 2], a.z);
            atomicAdd(&out[(size_t)cur * D + col + 3], a.w);
        }
    }
}

__global__ __launch_bounds__(NTHREADS) void seg_div_kernel(
    const int* __restrict__ len,
    float*     __restrict__ out,
    int total)
{
    const int i = blockIdx.x * blockDim.x + threadIdx.x;
    if (i < total) {
        out[i] = out[i] / (float)len[i >> 6];  // i>>6 == segment index (D=64)
    }
}

extern "C" void kernel_launch(void* const* d_in, const int* in_sizes, int n_in,
                              void* d_out, int out_size, void* d_ws, size_t ws_size,
                              hipStream_t stream) {
    const float* x   = (const float*)d_in[0];
    const int*   seg = (const int*)d_in[1];
    const int*   len = (const int*)d_in[2];
    float*       out = (float*)d_out;

    const int n_rows = in_sizes[1];       // N = 1048576
    const int B      = in_sizes[2];       // 64
    const int total  = B * D;             // 4096 == out_size

    // out doubles as the accumulator: zero it (out is poisoned before each call)
    hipMemsetAsync(out, 0, (size_t)total * sizeof(float), stream);

    const int grid = (n_rows + ROWS_PER_BLOCK - 1) / ROWS_PER_BLOCK;  // 2048
    seg_sum_kernel<<<grid, NTHREADS, 0, stream>>>(x, seg, out, n_rows);

    const int grid2 = (total + NTHREADS - 1) / NTHREADS;              // 16
    seg_div_kernel<<<grid2, NTHREADS, 0, stream>>>(len, out, total);
}